// Round 2
// baseline (6526.523 us; speedup 1.0000x reference)
//
#include <hip/hip_runtime.h>

// ---------- problem constants ----------
#define Bz   32
#define Pz   197
#define ENCz 768
#define EMBz 512
#define HIDz 512
#define ATTz 256
#define VOCz 32000
#define Tz   40

typedef unsigned short ushort_t;
typedef __attribute__((ext_vector_type(8))) short frag_ab;     // 8 bf16 (4 VGPRs)
typedef __attribute__((ext_vector_type(4))) float frag_cd;     // 4 fp32 acc
typedef __attribute__((ext_vector_type(4))) ushort_t ushort4v; // 8B
typedef __attribute__((ext_vector_type(8))) ushort_t ushort8v; // 16B

#define MFMA16(a, b, c) __builtin_amdgcn_mfma_f32_16x16x32_bf16((a), (b), (c), 0, 0, 0)

__device__ __forceinline__ float b2f(ushort_t u) {
    return __uint_as_float(((unsigned)u) << 16);
}
__device__ __forceinline__ ushort_t f2bf(float f) {
    unsigned u = __float_as_uint(f);
    unsigned r = (u + 0x7fffu + ((u >> 16) & 1u)) >> 16;
    return (ushort_t)r;
}
__device__ __forceinline__ float sigf(float x) { return 1.f / (1.f + __expf(-x)); }
__device__ __forceinline__ float tanhfast(float x) { return 1.f - 2.f / (__expf(2.f * x) + 1.f); }

// ---------- fp32 -> bf16 bulk convert (8 elems/thread) ----------
__global__ __launch_bounds__(256) void k_conv(const float* __restrict__ in, ushort_t* __restrict__ out) {
    size_t base = ((size_t)blockIdx.x * 256 + threadIdx.x) * 8;
    const float4* src = (const float4*)(in + base);
    float4 a = src[0], b = src[1];
    ushort8v v;
    v[0] = f2bf(a.x); v[1] = f2bf(a.y); v[2] = f2bf(a.z); v[3] = f2bf(a.w);
    v[4] = f2bf(b.x); v[5] = f2bf(b.y); v[6] = f2bf(b.z); v[7] = f2bf(b.w);
    *(ushort8v*)(out + base) = v;
}

// ---------- mean over P ----------
__global__ __launch_bounds__(256) void k_mean(const float* __restrict__ enc, float* __restrict__ meanE) {
    int e = blockIdx.x * 256 + threadIdx.x;      // 32*768 = 24576
    int b = e / ENCz, d = e % ENCz;
    const float* p = enc + (size_t)b * Pz * ENCz + d;
    float s = 0.f;
    for (int i = 0; i < Pz; ++i) s += p[i * ENCz];
    meanE[e] = s * (1.f / (float)Pz);
}

// ---------- h0/c0 init ----------
__global__ __launch_bounds__(256) void k_h0c0(const float* __restrict__ meanE,
                                              const float* __restrict__ W_inh, const float* __restrict__ b_inh,
                                              const float* __restrict__ W_inc, const float* __restrict__ b_inc,
                                              float* __restrict__ h_cur, float* __restrict__ c_cur,
                                              ushort_t* __restrict__ hA0) {
    __shared__ float msh[ENCz];
    int bid = blockIdx.x, tid = threadIdx.x;
    int b = bid >> 2, seg = bid & 3;             // seg0/1: h halves, seg2/3: c halves
    for (int i = tid; i < ENCz; i += 256) msh[i] = meanE[b * ENCz + i];
    __syncthreads();
    int col = (seg & 1) * 256 + tid;
    bool isc = (seg >> 1) != 0;
    const float* W = isc ? W_inc : W_inh;
    const float* bb = isc ? b_inc : b_inh;
    float acc = bb[col];
#pragma unroll 8
    for (int k = 0; k < ENCz; ++k) acc += msh[k] * W[k * HIDz + col];
    if (isc) c_cur[b * HIDz + col] = acc;
    else { h_cur[b * HIDz + col] = acc; hA0[b * HIDz + col] = f2bf(acc); }
}

// ---------- embedding gather+convert: Xemb[(t*32+b)] = bf16(emb[captions[b][t]]) ----------
__global__ __launch_bounds__(128) void k_gather(const int* __restrict__ captions, const float* __restrict__ emb,
                                                ushort_t* __restrict__ Xemb) {
    int row = blockIdx.x;                        // 0..1279 = t*32+b
    int t = row >> 5, b = row & 31;
    int cap = captions[b * 41 + t];
    float4 f = *(const float4*)(emb + (size_t)cap * EMBz + threadIdx.x * 4);
    ushort4v v; v[0] = f2bf(f.x); v[1] = f2bf(f.y); v[2] = f2bf(f.z); v[3] = f2bf(f.w);
    *(ushort4v*)(Xemb + (size_t)row * EMBz + threadIdx.x * 4) = v;
}

// ---------- fp32-in / bf16-out transpose: out[c][koff + r] = bf16(in[r][c]) ----------
__global__ __launch_bounds__(256) void k_transpose(const float* __restrict__ in, int R, int C,
                                                   ushort_t* __restrict__ out, int ldo, int koff) {
    __shared__ ushort_t tile[32][33];
    int c0 = blockIdx.x * 32, r0 = blockIdx.y * 32;
    int tx = threadIdx.x & 31, ty = threadIdx.x >> 5;    // ty 0..7
#pragma unroll
    for (int i = 0; i < 4; ++i) {
        int r = r0 + ty + i * 8;
        tile[ty + i * 8][tx] = f2bf(in[(size_t)r * C + c0 + tx]);
    }
    __syncthreads();
#pragma unroll
    for (int i = 0; i < 4; ++i) {
        int c = c0 + ty + i * 8;
        out[(size_t)c * ldo + koff + r0 + tx] = tile[tx][ty + i * 8];
    }
}

// ---------- MFMA GEMM: C[M x N] = A[M x lda(bf16)] * BT[N x K(bf16)]^T + bias(fp32) ----------
// MODE 0: fp32 out (ldo), bias1+bias2;  MODE 1: bf16 out (ldo), bias1, row-guard
// MODE 2: fp32 out permuted for final preds: row m = t*32+b -> out[b][t][n]
template <int MODE>
__global__ __launch_bounds__(256) void k_gemm(const ushort_t* __restrict__ A, int lda, int M,
                                              const ushort_t* __restrict__ BT, int K,
                                              const float* __restrict__ B1, const float* __restrict__ B2,
                                              void* __restrict__ out, int ldo) {
    __shared__ __align__(16) ushort_t As[128 * 64];
    __shared__ __align__(16) ushort_t Bs[128 * 64];
    const int tid = threadIdx.x;
    const int lane = tid & 63, w = tid >> 6;
    const int wm = w >> 1, wn = w & 1;
    const int n0 = blockIdx.x * 128, m0 = blockIdx.y * 128;
    const int quad = lane >> 4, c16 = lane & 15;

    frag_cd acc[4][4];
#pragma unroll
    for (int i = 0; i < 4; ++i)
#pragma unroll
        for (int j = 0; j < 4; ++j) acc[i][j] = (frag_cd){0.f, 0.f, 0.f, 0.f};

    for (int k0 = 0; k0 < K; k0 += 64) {
#pragma unroll
        for (int it = 0; it < 4; ++it) {
            int c = tid + it * 256;              // chunk 0..1023
            int row = c >> 3, col8 = (c & 7) * 8;
            int gr = m0 + row; gr = gr < M ? gr : M - 1;
            *(frag_ab*)&As[row * 64 + col8] = *(const frag_ab*)&A[(size_t)gr * lda + k0 + col8];
            *(frag_ab*)&Bs[row * 64 + col8] = *(const frag_ab*)&BT[(size_t)(n0 + row) * K + k0 + col8];
        }
        __syncthreads();
#pragma unroll
        for (int kk = 0; kk < 64; kk += 32) {
            int kcol = kk + quad * 8;
            frag_ab af[4], bf[4];
#pragma unroll
            for (int i = 0; i < 4; ++i) af[i] = *(const frag_ab*)&As[(wm * 64 + i * 16 + c16) * 64 + kcol];
#pragma unroll
            for (int j = 0; j < 4; ++j) bf[j] = *(const frag_ab*)&Bs[(wn * 64 + j * 16 + c16) * 64 + kcol];
#pragma unroll
            for (int i = 0; i < 4; ++i)
#pragma unroll
                for (int j = 0; j < 4; ++j) acc[i][j] = MFMA16(af[i], bf[j], acc[i][j]);
        }
        __syncthreads();
    }

#pragma unroll
    for (int i = 0; i < 4; ++i) {
#pragma unroll
        for (int j = 0; j < 4; ++j) {
            int n = n0 + wn * 64 + j * 16 + c16;
            float bias = B1[n];
            if (B2 != nullptr) bias += B2[n];
#pragma unroll
            for (int r = 0; r < 4; ++r) {
                int m = m0 + wm * 64 + i * 16 + quad * 4 + r;
                float v = acc[i][j][r] + bias;
                if (MODE == 0) {
                    if (m < M) ((float*)out)[(size_t)m * ldo + n] = v;
                } else if (MODE == 1) {
                    if (m < M) ((ushort_t*)out)[(size_t)m * ldo + n] = f2bf(v);
                } else {
                    int b = m & 31, t = m >> 5;
                    ((float*)out)[(size_t)b * (Tz * VOCz) + (size_t)t * VOCz + n] = v;
                }
            }
        }
    }
}

// ---------- per-step kernel A: attention (blocks 0..31) + gate sigma (blocks 32..127) ----------
__global__ __launch_bounds__(256) void k_step_a(const float* __restrict__ enc, const ushort_t* __restrict__ att1,
                                                const float* __restrict__ h_cur,
                                                const float* __restrict__ W_da, const float* __restrict__ b_da,
                                                const float* __restrict__ w_fa, const float* __restrict__ b_fa,
                                                const float* __restrict__ W_fb, const float* __restrict__ b_fb,
                                                float* __restrict__ awe_raw, float* __restrict__ graw) {
    __shared__ float hsh[HIDz];
    __shared__ float att2sh[ATTz];
    __shared__ float esh[256];
    __shared__ float wfash[ATTz];
    __shared__ float redsh[4];
    int tid = threadIdx.x, bid = blockIdx.x;
    int b = (bid < 32) ? bid : ((bid - 32) / 3);
    hsh[tid] = h_cur[b * HIDz + tid];
    hsh[tid + 256] = h_cur[b * HIDz + 256 + tid];
    __syncthreads();

    if (bid < 32) {
        // att2 = h @ W_da + b_da   (thread = one of 256 att cols)
        float acc = b_da[tid];
#pragma unroll 8
        for (int k = 0; k < HIDz; ++k) acc += hsh[k] * W_da[k * ATTz + tid];
        att2sh[tid] = acc;
        wfash[tid] = w_fa[tid];
        __syncthreads();
        // e[p] = relu(att1[b,p,:] + att2) . w_fa + b_fa
        int w = tid >> 6, lane = tid & 63;
        float bfa = b_fa[0];
        for (int p = w; p < Pz; p += 4) {
            const ushort_t* arow = att1 + ((size_t)(b * Pz + p)) * ATTz;
            float s = 0.f;
#pragma unroll
            for (int jj = 0; jj < 4; ++jj) {
                int j = lane + jj * 64;
                float t1 = b2f(arow[j]) + att2sh[j];
                s += fmaxf(t1, 0.f) * wfash[j];
            }
            for (int o = 32; o; o >>= 1) s += __shfl_down(s, o, 64);
            if (lane == 0) esh[p] = s + bfa;
        }
        __syncthreads();
        // softmax over 197
        float v = (tid < Pz) ? esh[tid] : -3.0e38f;
        for (int o = 32; o; o >>= 1) v = fmaxf(v, __shfl_down(v, o, 64));
        if (lane == 0) redsh[w] = v;
        __syncthreads();
        float mx = fmaxf(fmaxf(redsh[0], redsh[1]), fmaxf(redsh[2], redsh[3]));
        float ex = (tid < Pz) ? __expf(esh[tid] - mx) : 0.f;
        __syncthreads();                          // everyone done reading redsh
        float sv = ex;
        for (int o = 32; o; o >>= 1) sv += __shfl_down(sv, o, 64);
        if (lane == 0) redsh[w] = sv;
        __syncthreads();
        float inv = 1.f / (redsh[0] + redsh[1] + redsh[2] + redsh[3]);
        if (tid < Pz) esh[tid] = ex * inv;        // alpha
        __syncthreads();
        // awe[d] = sum_p alpha[p] * enc[b,p,d]
        for (int d = tid; d < ENCz; d += 256) {
            float a = 0.f;
            for (int p = 0; p < Pz; ++p) a += esh[p] * enc[((size_t)(b * Pz + p)) * ENCz + d];
            awe_raw[b * ENCz + d] = a;
        }
    } else {
        int g = bid - 32;
        int s3 = g - (g / 3) * 3;
        int col = s3 * 256 + tid;
        float acc = b_fb[col];
#pragma unroll 8
        for (int k = 0; k < HIDz; ++k) acc += hsh[k] * W_fb[k * ENCz + col];
        graw[b * ENCz + col] = sigf(acc);
    }
}

// ---------- per-step kernel B: gates = [g*awe | h] @ WgT^T + Xih[t]; LSTM cell ----------
// grid 32 blocks: block handles j in [bid*16, bid*16+16) across all 4 gate quadrants.
__global__ __launch_bounds__(256) void k_step_b(const float* __restrict__ awe_raw, const float* __restrict__ graw,
                                                const ushort_t* __restrict__ hA_r, ushort_t* __restrict__ hA_w,
                                                const ushort_t* __restrict__ WgT, const float* __restrict__ Xih_t,
                                                float* __restrict__ c_cur, float* __restrict__ h_cur,
                                                ushort_t* __restrict__ Hall_row) {
    __shared__ __align__(16) ushort_t Ach[32 * 136];     // staged bf16 gated-awe chunk (pad 136)
    __shared__ float gsh[4 * 32 * 16];                   // [q][b][jl]
    int tid = threadIdx.x;
    int lane = tid & 63, q = tid >> 6;                   // wave = quadrant
    int j0 = blockIdx.x * 16;
    int quad = lane >> 4, c16 = lane & 15;

    frag_cd acc0 = (frag_cd){0.f, 0.f, 0.f, 0.f};
    frag_cd acc1 = (frag_cd){0.f, 0.f, 0.f, 0.f};

    for (int c = 0; c < 10; ++c) {                       // K=1280 in chunks of 128 (0..5: awe, 6..9: h)
        if (c < 6) {
            int base = tid * 16;
            int b = base >> 7, kk = base & 127, k = c * 128 + kk;
            const float* ar = awe_raw + b * ENCz + k;
            const float* gr = graw + b * ENCz + k;
            ushort_t* dst = Ach + b * 136 + kk;
#pragma unroll
            for (int i = 0; i < 16; ++i) dst[i] = f2bf(ar[i] * gr[i]);
        }
        __syncthreads();
        int kq = quad * 8;
#pragma unroll
        for (int kk0 = 0; kk0 < 128; kk0 += 32) {
            frag_ab a0, a1, bfr;
            if (c < 6) {
                a0 = *(const frag_ab*)&Ach[c16 * 136 + kk0 + kq];
                a1 = *(const frag_ab*)&Ach[(16 + c16) * 136 + kk0 + kq];
            } else {
                int kh = c * 128 - 768 + kk0 + kq;
                a0 = *(const frag_ab*)&hA_r[c16 * HIDz + kh];
                a1 = *(const frag_ab*)&hA_r[(16 + c16) * HIDz + kh];
            }
            int n = q * 512 + j0 + c16;
            bfr = *(const frag_ab*)&WgT[(size_t)n * 1280 + c * 128 + kk0 + kq];
            acc0 = MFMA16(a0, bfr, acc0);
            acc1 = MFMA16(a1, bfr, acc1);
        }
        __syncthreads();
    }

#pragma unroll
    for (int r = 0; r < 4; ++r) {
        gsh[q * 512 + (quad * 4 + r) * 16 + c16] = acc0[r];
        gsh[q * 512 + (16 + quad * 4 + r) * 16 + c16] = acc1[r];
    }
    __syncthreads();
#pragma unroll
    for (int it = 0; it < 2; ++it) {
        int e = tid + it * 256;                          // 0..511
        int b = e >> 4, jl = e & 15, j = j0 + jl;
        float iv = gsh[0 * 512 + b * 16 + jl] + Xih_t[b * 2048 + j];
        float fv = gsh[1 * 512 + b * 16 + jl] + Xih_t[b * 2048 + 512 + j];
        float gv = gsh[2 * 512 + b * 16 + jl] + Xih_t[b * 2048 + 1024 + j];
        float ov = gsh[3 * 512 + b * 16 + jl] + Xih_t[b * 2048 + 1536 + j];
        float co = c_cur[b * HIDz + j];
        float cn = sigf(fv) * co + sigf(iv) * tanhfast(gv);
        float hn = sigf(ov) * tanhfast(cn);
        c_cur[b * HIDz + j] = cn;
        h_cur[b * HIDz + j] = hn;
        ushort_t hb = f2bf(hn);
        hA_w[b * HIDz + j] = hb;
        Hall_row[b * HIDz + j] = hb;
    }
}

// ---------- launcher ----------
extern "C" void kernel_launch(void* const* d_in, const int* in_sizes, int n_in,
                              void* d_out, int out_size, void* d_ws, size_t ws_size,
                              hipStream_t stream) {
    const float* enc   = (const float*)d_in[0];
    const int*   caps  = (const int*)d_in[1];
    const float* emb   = (const float*)d_in[2];
    const float* W_ea  = (const float*)d_in[3];
    const float* b_ea  = (const float*)d_in[4];
    const float* W_da  = (const float*)d_in[5];
    const float* b_da  = (const float*)d_in[6];
    const float* w_fa  = (const float*)d_in[7];
    const float* b_fa  = (const float*)d_in[8];
    const float* W_inh = (const float*)d_in[9];
    const float* b_inh = (const float*)d_in[10];
    const float* W_inc = (const float*)d_in[11];
    const float* b_inc = (const float*)d_in[12];
    const float* W_fb  = (const float*)d_in[13];
    const float* b_fb  = (const float*)d_in[14];
    const float* W_ih  = (const float*)d_in[15];
    const float* b_ih  = (const float*)d_in[16];
    const float* W_hh  = (const float*)d_in[17];
    const float* b_hh  = (const float*)d_in[18];
    const float* W_out = (const float*)d_in[19];
    const float* b_out = (const float*)d_in[20];

    char* ws = (char*)d_ws;
    ushort_t* att1    = (ushort_t*)(ws + 0);             // 6304x256 bf16
    ushort_t* Xemb    = (ushort_t*)(ws + 3227648);       // 1280x512 bf16
    ushort_t* encB    = (ushort_t*)(ws + 4538368);       // 32*197*768 bf16
    float*    Xih     = (float*)(ws + 14221312);         // 40x32x2048 fp32
    float*    meanE   = (float*)(ws + 24707072);         // 32x768
    float*    h_cur   = (float*)(ws + 24805376);         // 32x512
    float*    c_cur   = (float*)(ws + 24870912);         // 32x512
    float*    awe_raw = (float*)(ws + 24936448);         // 32x768
    float*    graw    = (float*)(ws + 25034752);         // 32x768
    ushort_t* hA0     = (ushort_t*)(ws + 25133056);      // 32x512 bf16
    ushort_t* hA1     = (ushort_t*)(ws + 25165824);      // 32x512 bf16
    ushort_t* Hall    = (ushort_t*)(ws + 25198592);      // 1280x512 bf16
    ushort_t* WgT     = (ushort_t*)(ws + 26509312);      // 2048x1280 bf16
    ushort_t* W_eaT   = (ushort_t*)(ws + 31752192);      // 256x768 bf16
    ushort_t* W_ihxT  = (ushort_t*)(ws + 32145408);      // 2048x512 bf16
    ushort_t* W_outT  = (ushort_t*)(ws + 34242560);      // 32000x512 bf16

    // precompute (order-independent, single stream)
    k_conv<<<2364, 256, 0, stream>>>(enc, encB);         // 32*197*768 = 2364*2048
    k_mean<<<96, 256, 0, stream>>>(enc, meanE);
    k_h0c0<<<128, 256, 0, stream>>>(meanE, W_inh, b_inh, W_inc, b_inc, h_cur, c_cur, hA0);
    k_gather<<<1280, 128, 0, stream>>>(caps, emb, Xemb);
    k_transpose<<<dim3(8, 24), 256, 0, stream>>>(W_ea, 768, 256, W_eaT, 768, 0);
    k_transpose<<<dim3(64, 16), 256, 0, stream>>>(W_ih, 512, 2048, W_ihxT, 512, 0);
    k_transpose<<<dim3(64, 24), 256, 0, stream>>>(W_ih + 512 * 2048, 768, 2048, WgT, 1280, 0);
    k_transpose<<<dim3(64, 16), 256, 0, stream>>>(W_hh, 512, 2048, WgT, 1280, 768);
    k_transpose<<<dim3(1000, 16), 256, 0, stream>>>(W_out, 512, 32000, W_outT, 512, 0);

    // att1 = enc @ W_ea + b_ea   (bf16 out)
    k_gemm<1><<<dim3(2, 50), 256, 0, stream>>>(encB, 768, 6304, W_eaT, 768, b_ea, nullptr, att1, 256);
    // Xih = Xemb @ W_ih[:512] + b_ih + b_hh  (fp32 out)
    k_gemm<0><<<dim3(16, 10), 256, 0, stream>>>(Xemb, 512, 1280, W_ihxT, 512, b_ih, b_hh, Xih, 2048);

    // recurrence
    for (int t = 0; t < Tz; ++t) {
        k_step_a<<<128, 256, 0, stream>>>(enc, att1, h_cur, W_da, b_da, w_fa, b_fa, W_fb, b_fb, awe_raw, graw);
        const ushort_t* hr = (t & 1) ? hA1 : hA0;
        ushort_t* hw = (t & 1) ? hA0 : hA1;
        k_step_b<<<32, 256, 0, stream>>>(awe_raw, graw, hr, hw, WgT, Xih + (size_t)t * 65536,
                                         c_cur, h_cur, Hall + (size_t)t * 16384);
    }

    // preds = Hall @ W_out + b_out -> d_out (B,T,V) fp32
    k_gemm<2><<<dim3(250, 10), 256, 0, stream>>>(Hall, 512, 1280, W_outT, 512, b_out, nullptr, d_out, VOCz);
}

// Round 3
// 2459.080 us; speedup vs baseline: 2.6541x; 2.6541x over previous
//
#include <hip/hip_runtime.h>

// ---------- problem constants ----------
#define Bz   32
#define Pz   197
#define ENCz 768
#define EMBz 512
#define HIDz 512
#define ATTz 256
#define VOCz 32000
#define Tz   40

typedef unsigned short ushort_t;
typedef __attribute__((ext_vector_type(8))) short frag_ab;     // 8 bf16 (4 VGPRs)
typedef __attribute__((ext_vector_type(4))) float frag_cd;     // 4 fp32 acc
typedef __attribute__((ext_vector_type(4))) ushort_t ushort4v; // 8B
typedef __attribute__((ext_vector_type(8))) ushort_t ushort8v; // 16B

#define MFMA16(a, b, c) __builtin_amdgcn_mfma_f32_16x16x32_bf16((a), (b), (c), 0, 0, 0)

__device__ __forceinline__ float b2f(ushort_t u) {
    return __uint_as_float(((unsigned)u) << 16);
}
__device__ __forceinline__ ushort_t f2bf(float f) {
    unsigned u = __float_as_uint(f);
    unsigned r = (u + 0x7fffu + ((u >> 16) & 1u)) >> 16;
    return (ushort_t)r;
}
__device__ __forceinline__ float sigf(float x) { return 1.f / (1.f + __expf(-x)); }
__device__ __forceinline__ float tanhfast(float x) { return 1.f - 2.f / (__expf(2.f * x) + 1.f); }

// ---------- fp32 -> bf16 bulk convert (8 elems/thread) ----------
__global__ __launch_bounds__(256) void k_conv(const float* __restrict__ in, ushort_t* __restrict__ out) {
    size_t base = ((size_t)blockIdx.x * 256 + threadIdx.x) * 8;
    const float4* src = (const float4*)(in + base);
    float4 a = src[0], b = src[1];
    ushort8v v;
    v[0] = f2bf(a.x); v[1] = f2bf(a.y); v[2] = f2bf(a.z); v[3] = f2bf(a.w);
    v[4] = f2bf(b.x); v[5] = f2bf(b.y); v[6] = f2bf(b.z); v[7] = f2bf(b.w);
    *(ushort8v*)(out + base) = v;
}

// ---------- mean over P ----------
__global__ __launch_bounds__(256) void k_mean(const float* __restrict__ enc, float* __restrict__ meanE) {
    int e = blockIdx.x * 256 + threadIdx.x;      // 32*768 = 24576
    int b = e / ENCz, d = e % ENCz;
    const float* p = enc + (size_t)b * Pz * ENCz + d;
    float s = 0.f;
    for (int i = 0; i < Pz; ++i) s += p[i * ENCz];
    meanE[e] = s * (1.f / (float)Pz);
}

// ---------- h0/c0 init ----------
__global__ __launch_bounds__(256) void k_h0c0(const float* __restrict__ meanE,
                                              const float* __restrict__ W_inh, const float* __restrict__ b_inh,
                                              const float* __restrict__ W_inc, const float* __restrict__ b_inc,
                                              float* __restrict__ h_cur, float* __restrict__ c_cur,
                                              ushort_t* __restrict__ hA0) {
    __shared__ float msh[ENCz];
    int bid = blockIdx.x, tid = threadIdx.x;
    int b = bid >> 2, seg = bid & 3;             // seg0/1: h halves, seg2/3: c halves
    for (int i = tid; i < ENCz; i += 256) msh[i] = meanE[b * ENCz + i];
    __syncthreads();
    int col = (seg & 1) * 256 + tid;
    bool isc = (seg >> 1) != 0;
    const float* W = isc ? W_inc : W_inh;
    const float* bb = isc ? b_inc : b_inh;
    float a0 = 0.f, a1 = 0.f, a2 = 0.f, a3 = 0.f;
    for (int k = 0; k < ENCz; k += 4) {
        a0 += msh[k + 0] * W[(k + 0) * HIDz + col];
        a1 += msh[k + 1] * W[(k + 1) * HIDz + col];
        a2 += msh[k + 2] * W[(k + 2) * HIDz + col];
        a3 += msh[k + 3] * W[(k + 3) * HIDz + col];
    }
    float acc = a0 + a1 + a2 + a3 + bb[col];
    if (isc) c_cur[b * HIDz + col] = acc;
    else { h_cur[b * HIDz + col] = acc; hA0[b * HIDz + col] = f2bf(acc); }
}

// ---------- embedding gather+convert: Xemb[(t*32+b)] = bf16(emb[captions[b][t]]) ----------
__global__ __launch_bounds__(128) void k_gather(const int* __restrict__ captions, const float* __restrict__ emb,
                                                ushort_t* __restrict__ Xemb) {
    int row = blockIdx.x;                        // 0..1279 = t*32+b
    int t = row >> 5, b = row & 31;
    int cap = captions[b * 41 + t];
    float4 f = *(const float4*)(emb + (size_t)cap * EMBz + threadIdx.x * 4);
    ushort4v v; v[0] = f2bf(f.x); v[1] = f2bf(f.y); v[2] = f2bf(f.z); v[3] = f2bf(f.w);
    *(ushort4v*)(Xemb + (size_t)row * EMBz + threadIdx.x * 4) = v;
}

// ---------- fp32-in / bf16-out transpose: out[c][koff + r] = bf16(in[r][c]) ----------
__global__ __launch_bounds__(256) void k_transpose(const float* __restrict__ in, int R, int C,
                                                   ushort_t* __restrict__ out, int ldo, int koff) {
    __shared__ ushort_t tile[32][33];
    int c0 = blockIdx.x * 32, r0 = blockIdx.y * 32;
    int tx = threadIdx.x & 31, ty = threadIdx.x >> 5;    // ty 0..7
#pragma unroll
    for (int i = 0; i < 4; ++i) {
        int r = r0 + ty + i * 8;
        tile[ty + i * 8][tx] = f2bf(in[(size_t)r * C + c0 + tx]);
    }
    __syncthreads();
#pragma unroll
    for (int i = 0; i < 4; ++i) {
        int c = c0 + ty + i * 8;
        out[(size_t)c * ldo + koff + r0 + tx] = tile[tx][ty + i * 8];
    }
}

// ---------- MFMA GEMM: C[M x N] = A[M x lda(bf16)] * BT[N x K(bf16)]^T + bias(fp32) ----------
// MODE 0: fp32 out (ldo), bias1+bias2;  MODE 1: bf16 out (ldo), bias1, row-guard
// MODE 2: fp32 out permuted for final preds: row m = t*32+b -> out[b][t][n]
template <int MODE>
__global__ __launch_bounds__(256) void k_gemm(const ushort_t* __restrict__ A, int lda, int M,
                                              const ushort_t* __restrict__ BT, int K,
                                              const float* __restrict__ B1, const float* __restrict__ B2,
                                              void* __restrict__ out, int ldo) {
    __shared__ __align__(16) ushort_t As[128 * 64];
    __shared__ __align__(16) ushort_t Bs[128 * 64];
    const int tid = threadIdx.x;
    const int lane = tid & 63, w = tid >> 6;
    const int wm = w >> 1, wn = w & 1;
    const int n0 = blockIdx.x * 128, m0 = blockIdx.y * 128;
    const int quad = lane >> 4, c16 = lane & 15;

    frag_cd acc[4][4];
#pragma unroll
    for (int i = 0; i < 4; ++i)
#pragma unroll
        for (int j = 0; j < 4; ++j) acc[i][j] = (frag_cd){0.f, 0.f, 0.f, 0.f};

    for (int k0 = 0; k0 < K; k0 += 64) {
#pragma unroll
        for (int it = 0; it < 4; ++it) {
            int c = tid + it * 256;              // chunk 0..1023
            int row = c >> 3, col8 = (c & 7) * 8;
            int gr = m0 + row; gr = gr < M ? gr : M - 1;
            *(frag_ab*)&As[row * 64 + col8] = *(const frag_ab*)&A[(size_t)gr * lda + k0 + col8];
            *(frag_ab*)&Bs[row * 64 + col8] = *(const frag_ab*)&BT[(size_t)(n0 + row) * K + k0 + col8];
        }
        __syncthreads();
#pragma unroll
        for (int kk = 0; kk < 64; kk += 32) {
            int kcol = kk + quad * 8;
            frag_ab af[4], bf[4];
#pragma unroll
            for (int i = 0; i < 4; ++i) af[i] = *(const frag_ab*)&As[(wm * 64 + i * 16 + c16) * 64 + kcol];
#pragma unroll
            for (int j = 0; j < 4; ++j) bf[j] = *(const frag_ab*)&Bs[(wn * 64 + j * 16 + c16) * 64 + kcol];
#pragma unroll
            for (int i = 0; i < 4; ++i)
#pragma unroll
                for (int j = 0; j < 4; ++j) acc[i][j] = MFMA16(af[i], bf[j], acc[i][j]);
        }
        __syncthreads();
    }

#pragma unroll
    for (int i = 0; i < 4; ++i) {
#pragma unroll
        for (int j = 0; j < 4; ++j) {
            int n = n0 + wn * 64 + j * 16 + c16;
            float bias = B1[n];
            if (B2 != nullptr) bias += B2[n];
#pragma unroll
            for (int r = 0; r < 4; ++r) {
                int m = m0 + wm * 64 + i * 16 + quad * 4 + r;
                float v = acc[i][j][r] + bias;
                if (MODE == 0) {
                    if (m < M) ((float*)out)[(size_t)m * ldo + n] = v;
                } else if (MODE == 1) {
                    if (m < M) ((ushort_t*)out)[(size_t)m * ldo + n] = f2bf(v);
                } else {
                    int b = m & 31, t = m >> 5;
                    ((float*)out)[(size_t)b * (Tz * VOCz) + (size_t)t * VOCz + n] = v;
                }
            }
        }
    }
}

// ---------- per-step kernel E: e-scores (blocks 0..63) + awe zeroing (64..71) + gate (72..167) ----------
__global__ __launch_bounds__(256) void k_step_e(const ushort_t* __restrict__ att1, const float* __restrict__ h_cur,
                                                const float* __restrict__ W_da, const float* __restrict__ b_da,
                                                const float* __restrict__ w_fa, const float* __restrict__ b_fa,
                                                const float* __restrict__ W_fb, const float* __restrict__ b_fb,
                                                float* __restrict__ e_out, float* __restrict__ awe_raw,
                                                float* __restrict__ graw) {
    __shared__ float hsh[HIDz];
    __shared__ float att2sh[ATTz];
    __shared__ float wfash[ATTz];
    int bid = blockIdx.x, tid = threadIdx.x;

    if (bid < 64) {
        int b = bid >> 1, ph = bid & 1;
        hsh[tid] = h_cur[b * HIDz + tid];
        hsh[tid + 256] = h_cur[b * HIDz + 256 + tid];
        __syncthreads();
        float a0 = 0.f, a1 = 0.f, a2 = 0.f, a3 = 0.f;
        for (int k = 0; k < HIDz; k += 4) {
            a0 += hsh[k + 0] * W_da[(k + 0) * ATTz + tid];
            a1 += hsh[k + 1] * W_da[(k + 1) * ATTz + tid];
            a2 += hsh[k + 2] * W_da[(k + 2) * ATTz + tid];
            a3 += hsh[k + 3] * W_da[(k + 3) * ATTz + tid];
        }
        att2sh[tid] = a0 + a1 + a2 + a3 + b_da[tid];
        wfash[tid] = w_fa[tid];
        __syncthreads();
        int w = tid >> 6, lane = tid & 63;
        float bfa = b_fa[0];
        int p0 = ph * 99, pend = ph ? Pz : 99;
        for (int p = p0 + w; p < pend; p += 4) {
            const ushort_t* arow = att1 + ((size_t)(b * Pz + p)) * ATTz;
            float s = 0.f;
#pragma unroll
            for (int jj = 0; jj < 4; ++jj) {
                int j = lane + jj * 64;
                float t1 = b2f(arow[j]) + att2sh[j];
                s += fmaxf(t1, 0.f) * wfash[j];
            }
            for (int o = 32; o; o >>= 1) s += __shfl_down(s, o, 64);
            if (lane == 0) e_out[b * Pz + p] = s + bfa;
        }
    } else if (bid < 72) {
        int i = (bid - 64) * 3072 + tid * 12;    // 8*256*12 = 24576 = 32*768
        float4 z = {0.f, 0.f, 0.f, 0.f};
        float4* dst = (float4*)(awe_raw + i);
        dst[0] = z; dst[1] = z; dst[2] = z;
    } else {
        int g = bid - 72;                        // 0..95
        int b = g / 3, seg = g - (g / 3) * 3;
        hsh[tid] = h_cur[b * HIDz + tid];
        hsh[tid + 256] = h_cur[b * HIDz + 256 + tid];
        __syncthreads();
        int col = seg * 256 + tid;
        float a0 = 0.f, a1 = 0.f, a2 = 0.f, a3 = 0.f;
        for (int k = 0; k < HIDz; k += 4) {
            a0 += hsh[k + 0] * W_fb[(k + 0) * ENCz + col];
            a1 += hsh[k + 1] * W_fb[(k + 1) * ENCz + col];
            a2 += hsh[k + 2] * W_fb[(k + 2) * ENCz + col];
            a3 += hsh[k + 3] * W_fb[(k + 3) * ENCz + col];
        }
        graw[b * ENCz + col] = sigf(a0 + a1 + a2 + a3 + b_fb[col]);
    }
}

// ---------- per-step kernel AWE: softmax (redundant per block) + partial awe, 256 blocks ----------
__global__ __launch_bounds__(256) void k_step_awe(const float* __restrict__ enc, const float* __restrict__ e_in,
                                                  float* __restrict__ awe_raw) {
    __shared__ float esh[200];
    __shared__ float alpha_sh[25];
    __shared__ float red[8];
    int bid = blockIdx.x, tid = threadIdx.x;
    int b = bid >> 3, pc = bid & 7;
    int p0 = pc * 25;
    int pn = Pz - p0 < 25 ? Pz - p0 : 25;        // pc=7 -> 22
    if (tid < Pz) esh[tid] = e_in[b * Pz + tid];
    __syncthreads();
    int w = tid >> 6, lane = tid & 63;
    float v = (tid < Pz) ? esh[tid] : -3.0e38f;
    for (int o = 32; o; o >>= 1) v = fmaxf(v, __shfl_down(v, o, 64));
    if (lane == 0) red[w] = v;
    __syncthreads();
    float mx = fmaxf(fmaxf(red[0], red[1]), fmaxf(red[2], red[3]));
    float ex = (tid < Pz) ? __expf(esh[tid] - mx) : 0.f;
    float sv = ex;
    for (int o = 32; o; o >>= 1) sv += __shfl_down(sv, o, 64);
    if (lane == 0) red[4 + w] = sv;
    __syncthreads();
    float inv = 1.f / (red[4] + red[5] + red[6] + red[7]);
    if (tid >= p0 && tid < p0 + pn) alpha_sh[tid - p0] = ex * inv;
    __syncthreads();
    if (tid < 192) {
        const float4* ep = (const float4*)(enc + ((size_t)(b * Pz + p0)) * ENCz) + tid;
        float4 acc = {0.f, 0.f, 0.f, 0.f};
        for (int i = 0; i < pn; ++i) {
            float al = alpha_sh[i];
            float4 ev = ep[(size_t)i * 192];
            acc.x += al * ev.x; acc.y += al * ev.y; acc.z += al * ev.z; acc.w += al * ev.w;
        }
        float* dst = awe_raw + b * ENCz + tid * 4;
        atomicAdd(dst + 0, acc.x); atomicAdd(dst + 1, acc.y);
        atomicAdd(dst + 2, acc.z); atomicAdd(dst + 3, acc.w);
    }
}

// ---------- per-step kernel B: gates = [g*awe | h] @ WgT^T + Xih[t]; LSTM cell ----------
// 64 blocks: bid>>1 = j-tile (16 cols), bid&1 = m-half (16 batch rows).
__global__ __launch_bounds__(256) void k_step_b(const float* __restrict__ awe_raw, const float* __restrict__ graw,
                                                const ushort_t* __restrict__ hA_r, ushort_t* __restrict__ hA_w,
                                                const ushort_t* __restrict__ WgT, const float* __restrict__ Xih_t,
                                                float* __restrict__ c_cur, float* __restrict__ h_cur,
                                                ushort_t* __restrict__ Hall_row) {
    __shared__ __align__(16) ushort_t Ach[16 * 136];     // staged bf16 gated-awe chunk (pad 136)
    __shared__ float gsh[4 * 16 * 16];                   // [q][b_l][jl]
    int tid = threadIdx.x;
    int lane = tid & 63, q = tid >> 6;                   // wave = quadrant
    int j0 = (blockIdx.x >> 1) * 16;
    int mb = (blockIdx.x & 1) * 16;
    int quad = lane >> 4, c16 = lane & 15;

    frag_cd acc0 = (frag_cd){0.f, 0.f, 0.f, 0.f};

    for (int c = 0; c < 10; ++c) {                       // K=1280 in chunks of 128 (0..5: awe, 6..9: h)
        if (c < 6 && tid < 128) {
            int base = tid * 16;
            int bl = base >> 7, kk = base & 127, k = c * 128 + kk;
            int b = mb + bl;
            const float* ar = awe_raw + b * ENCz + k;
            const float* gr = graw + b * ENCz + k;
            ushort_t* dst = Ach + bl * 136 + kk;
#pragma unroll
            for (int i = 0; i < 16; ++i) dst[i] = f2bf(ar[i] * gr[i]);
        }
        __syncthreads();
        int kq = quad * 8;
#pragma unroll
        for (int kk0 = 0; kk0 < 128; kk0 += 32) {
            frag_ab a0, bfr;
            if (c < 6) {
                a0 = *(const frag_ab*)&Ach[c16 * 136 + kk0 + kq];
            } else {
                int kh = c * 128 - 768 + kk0 + kq;
                a0 = *(const frag_ab*)&hA_r[(mb + c16) * HIDz + kh];
            }
            int n = q * 512 + j0 + c16;
            bfr = *(const frag_ab*)&WgT[(size_t)n * 1280 + c * 128 + kk0 + kq];
            acc0 = MFMA16(a0, bfr, acc0);
        }
        __syncthreads();
    }

#pragma unroll
    for (int r = 0; r < 4; ++r)
        gsh[q * 256 + (quad * 4 + r) * 16 + c16] = acc0[r];
    __syncthreads();
    {
        int bl = tid >> 4, jl = tid & 15;
        int b = mb + bl, j = j0 + jl;
        float iv = gsh[0 * 256 + bl * 16 + jl] + Xih_t[b * 2048 + j];
        float fv = gsh[1 * 256 + bl * 16 + jl] + Xih_t[b * 2048 + 512 + j];
        float gv = gsh[2 * 256 + bl * 16 + jl] + Xih_t[b * 2048 + 1024 + j];
        float ov = gsh[3 * 256 + bl * 16 + jl] + Xih_t[b * 2048 + 1536 + j];
        float co = c_cur[b * HIDz + j];
        float cn = sigf(fv) * co + sigf(iv) * tanhfast(gv);
        float hn = sigf(ov) * tanhfast(cn);
        c_cur[b * HIDz + j] = cn;
        h_cur[b * HIDz + j] = hn;
        ushort_t hb = f2bf(hn);
        hA_w[b * HIDz + j] = hb;
        Hall_row[b * HIDz + j] = hb;
    }
}

// ---------- launcher ----------
extern "C" void kernel_launch(void* const* d_in, const int* in_sizes, int n_in,
                              void* d_out, int out_size, void* d_ws, size_t ws_size,
                              hipStream_t stream) {
    const float* enc   = (const float*)d_in[0];
    const int*   caps  = (const int*)d_in[1];
    const float* emb   = (const float*)d_in[2];
    const float* W_ea  = (const float*)d_in[3];
    const float* b_ea  = (const float*)d_in[4];
    const float* W_da  = (const float*)d_in[5];
    const float* b_da  = (const float*)d_in[6];
    const float* w_fa  = (const float*)d_in[7];
    const float* b_fa  = (const float*)d_in[8];
    const float* W_inh = (const float*)d_in[9];
    const float* b_inh = (const float*)d_in[10];
    const float* W_inc = (const float*)d_in[11];
    const float* b_inc = (const float*)d_in[12];
    const float* W_fb  = (const float*)d_in[13];
    const float* b_fb  = (const float*)d_in[14];
    const float* W_ih  = (const float*)d_in[15];
    const float* b_ih  = (const float*)d_in[16];
    const float* W_hh  = (const float*)d_in[17];
    const float* b_hh  = (const float*)d_in[18];
    const float* W_out = (const float*)d_in[19];
    const float* b_out = (const float*)d_in[20];

    char* ws = (char*)d_ws;
    ushort_t* att1    = (ushort_t*)(ws + 0);             // 6304x256 bf16
    ushort_t* Xemb    = (ushort_t*)(ws + 3227648);       // 1280x512 bf16
    ushort_t* encB    = (ushort_t*)(ws + 4538368);       // 32*197*768 bf16
    float*    Xih     = (float*)(ws + 14221312);         // 40x32x2048 fp32
    float*    meanE   = (float*)(ws + 24707072);         // 32x768 (reused as e_buf after init)
    float*    h_cur   = (float*)(ws + 24805376);         // 32x512
    float*    c_cur   = (float*)(ws + 24870912);         // 32x512
    float*    awe_raw = (float*)(ws + 24936448);         // 32x768
    float*    graw    = (float*)(ws + 25034752);         // 32x768
    ushort_t* hA0     = (ushort_t*)(ws + 25133056);      // 32x512 bf16
    ushort_t* hA1     = (ushort_t*)(ws + 25165824);      // 32x512 bf16
    ushort_t* Hall    = (ushort_t*)(ws + 25198592);      // 1280x512 bf16
    ushort_t* WgT     = (ushort_t*)(ws + 26509312);      // 2048x1280 bf16
    ushort_t* W_eaT   = (ushort_t*)(ws + 31752192);      // 256x768 bf16
    ushort_t* W_ihxT  = (ushort_t*)(ws + 32145408);      // 2048x512 bf16
    ushort_t* W_outT  = (ushort_t*)(ws + 34242560);      // 32000x512 bf16
    float*    e_buf   = meanE;                           // 32x197 fp32 (25KB < 96KB; meanE dead after k_h0c0)

    // precompute (order-independent, single stream)
    k_conv<<<2364, 256, 0, stream>>>(enc, encB);         // 32*197*768 = 2364*2048
    k_mean<<<96, 256, 0, stream>>>(enc, meanE);
    k_h0c0<<<128, 256, 0, stream>>>(meanE, W_inh, b_inh, W_inc, b_inc, h_cur, c_cur, hA0);
    k_gather<<<1280, 128, 0, stream>>>(caps, emb, Xemb);
    k_transpose<<<dim3(8, 24), 256, 0, stream>>>(W_ea, 768, 256, W_eaT, 768, 0);
    k_transpose<<<dim3(64, 16), 256, 0, stream>>>(W_ih, 512, 2048, W_ihxT, 512, 0);
    k_transpose<<<dim3(64, 24), 256, 0, stream>>>(W_ih + 512 * 2048, 768, 2048, WgT, 1280, 0);
    k_transpose<<<dim3(64, 16), 256, 0, stream>>>(W_hh, 512, 2048, WgT, 1280, 768);
    k_transpose<<<dim3(1000, 16), 256, 0, stream>>>(W_out, 512, 32000, W_outT, 512, 0);

    // att1 = enc @ W_ea + b_ea   (bf16 out)
    k_gemm<1><<<dim3(2, 50), 256, 0, stream>>>(encB, 768, 6304, W_eaT, 768, b_ea, nullptr, att1, 256);
    // Xih = Xemb @ W_ih[:512] + b_ih + b_hh  (fp32 out)
    k_gemm<0><<<dim3(16, 10), 256, 0, stream>>>(Xemb, 512, 1280, W_ihxT, 512, b_ih, b_hh, Xih, 2048);

    // recurrence
    for (int t = 0; t < Tz; ++t) {
        k_step_e<<<168, 256, 0, stream>>>(att1, h_cur, W_da, b_da, w_fa, b_fa, W_fb, b_fb,
                                          e_buf, awe_raw, graw);
        k_step_awe<<<256, 256, 0, stream>>>(enc, e_buf, awe_raw);
        const ushort_t* hr = (t & 1) ? hA1 : hA0;
        ushort_t* hw = (t & 1) ? hA0 : hA1;
        k_step_b<<<64, 256, 0, stream>>>(awe_raw, graw, hr, hw, WgT, Xih + (size_t)t * 65536,
                                         c_cur, h_cur, Hall + (size_t)t * 16384);
    }

    // preds = Hall @ W_out + b_out -> d_out (B,T,V) fp32
    k_gemm<2><<<dim3(250, 10), 256, 0, stream>>>(Hall, 512, 1280, W_outT, 512, b_out, nullptr, d_out, VOCz);
}